// Round 1
// baseline (8735.368 us; speedup 1.0000x reference)
//
#include <hip/hip_runtime.h>
#include <hip/hip_bf16.h>
#include <math.h>

// Problem constants (NemotronHMoE): B=2,S=2048,H=2048,E=32,I=1024,SI=4096,K=4,G=4,TKG=2,scale=2.5
#define H_DIM 2048
#define E_NUM 32
#define I_DIM 1024
#define SI_DIM 4096
#define T_TOT 4096
#define K_SEL 4
#define G_NUM 4
#define SCALE_F 2.5f

// ---------------- Router: logits -> sigmoid -> group-limited top-k ----------------
// One block (64 threads = 1 wave) per token. Lanes 0..31 own expert e = lane for the
// 2nd half-H partial; selection is serialized on lane 0 over 32 experts (tiny).
__global__ __launch_bounds__(64) void router_kernel(
    const float* __restrict__ x, const float* __restrict__ gw,
    const float* __restrict__ ebias, int* __restrict__ counts,
    int* __restrict__ list, float* __restrict__ topkw)
{
    const int t = blockIdx.x;
    const int lane = threadIdx.x;
    const int e = lane & 31;
    const int half = lane >> 5;

    const float* xr = x + (size_t)t * H_DIM + half * 1024;
    const float* gwr = gw + (size_t)half * 1024 * E_NUM + e;
    float acc = 0.f;
#pragma unroll 8
    for (int h = 0; h < 1024; ++h)
        acc = fmaf(xr[h], gwr[(size_t)h * E_NUM], acc);
    acc += __shfl_xor(acc, 32);   // combine the two H-halves

    __shared__ float score_s[32];
    __shared__ float sfc_s[32];
    if (lane < 32) {
        float sc = 1.f / (1.f + expf(-acc));   // sigmoid
        score_s[e] = sc;
        sfc_s[e] = sc + ebias[e];
    }
    __syncthreads();

    if (lane == 0) {
        // group score = sum of top-2 sfc within each group of 8
        float gs[G_NUM];
#pragma unroll
        for (int g = 0; g < G_NUM; ++g) {
            float m1 = -1e30f, m2 = -1e30f;
#pragma unroll
            for (int j = 0; j < 8; ++j) {
                float v = sfc_s[g * 8 + j];
                if (v > m1) { m2 = m1; m1 = v; }
                else if (v > m2) { m2 = v; }
            }
            gs[g] = m1 + m2;
        }
        // top-2 groups (jax top_k: ties -> lower index, so strict >)
        int g1 = 0; float b1 = gs[0];
#pragma unroll
        for (int g = 1; g < G_NUM; ++g) if (gs[g] > b1) { b1 = gs[g]; g1 = g; }
        int g2 = 0; float b2 = -1e30f;
#pragma unroll
        for (int g = 0; g < G_NUM; ++g) if (g != g1 && gs[g] > b2) { b2 = gs[g]; g2 = g; }
        unsigned gmask = (0xFFu << (g1 * 8)) | (0xFFu << (g2 * 8)); // expert-level mask

        // top-4 experts over masked sfc (masked entries compare as 0.0, like reference)
        unsigned picked = 0;
        int eidx[K_SEL]; float wk[K_SEL]; float wsum = 0.f;
#pragma unroll
        for (int k = 0; k < K_SEL; ++k) {
            float best = -1e30f; int bi = 0;
            for (int ee = 0; ee < 32; ++ee) {
                if (picked & (1u << ee)) continue;
                float v = ((gmask >> ee) & 1u) ? sfc_s[ee] : 0.f;
                if (v > best) { best = v; bi = ee; }
            }
            picked |= 1u << bi;
            eidx[k] = bi;
            float w = score_s[bi];   // unbiased sigmoid score
            wk[k] = w; wsum += w;
        }
        float inv = SCALE_F / (wsum + 1e-20f);
#pragma unroll
        for (int k = 0; k < K_SEL; ++k) {
            int p = t * K_SEL + k;                 // pair id encodes (t,k)
            topkw[p] = wk[k] * inv;
            int ee = eidx[k];
            int pos = atomicAdd(&counts[ee], 1);
            list[ee * T_TOT + pos] = p;
        }
    }
}

// ---------------- f32 tiled GEMM building block: 64x64 tile, BK=16, 256 thr, 4x4 micro ----
// As padded to [16][68]: staging writes land 2-way (free), float4 reads conflict-free,
// rows are 272B = 17*16B so &As[kk][4*ty] stays 16B-aligned.

// shared expert up: hs[t-t0, :] = relu2(x[t,:] @ Wsu)
__global__ __launch_bounds__(256) void shared_up_kernel(
    const float* __restrict__ x, const float* __restrict__ Wsu,
    float* __restrict__ hs, int t0, int t1)
{
    __shared__ float As[16][68];
    __shared__ float Bs[16][64];
    const int crow0 = blockIdx.x * 64;          // chunk-local row
    const int n0 = blockIdx.y * 64;
    const int tid = threadIdx.x;
    const int tx = tid & 15, ty = tid >> 4;
    const int ar = tid >> 4, ak = tid & 15;
    const int bk = tid >> 6, bj = tid & 63;
    float acc[4][4] = {};
    for (int k0 = 0; k0 < H_DIM; k0 += 16) {
#pragma unroll
        for (int q = 0; q < 4; ++q) {
            int i = ar + q * 16;
            int t = t0 + crow0 + i;
            As[ak][i] = (t < t1) ? x[(size_t)t * H_DIM + k0 + ak] : 0.f;
        }
#pragma unroll
        for (int q = 0; q < 4; ++q) {
            int kk = bk + q * 4;
            Bs[kk][bj] = Wsu[(size_t)(k0 + kk) * SI_DIM + n0 + bj];
        }
        __syncthreads();
#pragma unroll
        for (int kk = 0; kk < 16; ++kk) {
            const float4 a4 = *(const float4*)&As[kk][ty * 4];
            const float4 b4 = *(const float4*)&Bs[kk][tx * 4];
            const float av[4] = {a4.x, a4.y, a4.z, a4.w};
            const float bv[4] = {b4.x, b4.y, b4.z, b4.w};
#pragma unroll
            for (int ii = 0; ii < 4; ++ii)
#pragma unroll
                for (int jj = 0; jj < 4; ++jj)
                    acc[ii][jj] = fmaf(av[ii], bv[jj], acc[ii][jj]);
        }
        __syncthreads();
    }
#pragma unroll
    for (int ii = 0; ii < 4; ++ii) {
        int t = t0 + crow0 + ty * 4 + ii;
        if (t >= t1) continue;
        size_t base = (size_t)(t - t0) * SI_DIM + n0 + tx * 4;
#pragma unroll
        for (int jj = 0; jj < 4; ++jj) {
            float r = acc[ii][jj];
            hs[base + jj] = r > 0.f ? r * r : 0.f;
        }
    }
}

// shared expert down: out[t, :] = hs[t-t0, :] @ Wsd   (initializes out)
__global__ __launch_bounds__(256) void shared_down_kernel(
    const float* __restrict__ hs, const float* __restrict__ Wsd,
    float* __restrict__ out, int t0, int t1)
{
    __shared__ float As[16][68];
    __shared__ float Bs[16][64];
    const int crow0 = blockIdx.x * 64;
    const int n0 = blockIdx.y * 64;
    const int tid = threadIdx.x;
    const int tx = tid & 15, ty = tid >> 4;
    const int ar = tid >> 4, ak = tid & 15;
    const int bk = tid >> 6, bj = tid & 63;
    float acc[4][4] = {};
    for (int k0 = 0; k0 < SI_DIM; k0 += 16) {
#pragma unroll
        for (int q = 0; q < 4; ++q) {
            int i = ar + q * 16;
            int t = t0 + crow0 + i;
            As[ak][i] = (t < t1) ? hs[(size_t)(crow0 + i) * SI_DIM + k0 + ak] : 0.f;
        }
#pragma unroll
        for (int q = 0; q < 4; ++q) {
            int kk = bk + q * 4;
            Bs[kk][bj] = Wsd[(size_t)(k0 + kk) * H_DIM + n0 + bj];
        }
        __syncthreads();
#pragma unroll
        for (int kk = 0; kk < 16; ++kk) {
            const float4 a4 = *(const float4*)&As[kk][ty * 4];
            const float4 b4 = *(const float4*)&Bs[kk][tx * 4];
            const float av[4] = {a4.x, a4.y, a4.z, a4.w};
            const float bv[4] = {b4.x, b4.y, b4.z, b4.w};
#pragma unroll
            for (int ii = 0; ii < 4; ++ii)
#pragma unroll
                for (int jj = 0; jj < 4; ++jj)
                    acc[ii][jj] = fmaf(av[ii], bv[jj], acc[ii][jj]);
        }
        __syncthreads();
    }
#pragma unroll
    for (int ii = 0; ii < 4; ++ii) {
        int t = t0 + crow0 + ty * 4 + ii;
        if (t >= t1) continue;
        size_t base = (size_t)t * H_DIM + n0 + tx * 4;
#pragma unroll
        for (int jj = 0; jj < 4; ++jj)
            out[base + jj] = acc[ii][jj];
    }
}

// routed up: act[p - 4*t0, :] = relu2(x[t(p), :] @ Wu[e]) for pairs p in expert e's list
__global__ __launch_bounds__(256) void routed_up_kernel(
    const float* __restrict__ x, const float* __restrict__ Wu,
    const int* __restrict__ counts, const int* __restrict__ list,
    float* __restrict__ act, int t0, int t1)
{
    const int e = blockIdx.z;
    const int cnt = counts[e];
    const int m0 = blockIdx.x * 64;
    if (m0 >= cnt) return;

    __shared__ int plist[64];
    __shared__ float As[16][68];
    __shared__ float Bs[16][64];
    const int tid = threadIdx.x;
    if (tid < 64) {
        int p = -1;
        if (m0 + tid < cnt) {
            p = list[e * T_TOT + m0 + tid];
            int t = p >> 2;
            if (t < t0 || t >= t1) p = -1;   // outside this chunk
        }
        plist[tid] = p;
    }
    __syncthreads();

    const int n0 = blockIdx.y * 64;
    const int tx = tid & 15, ty = tid >> 4;
    const int ar = tid >> 4, ak = tid & 15;
    const int bk = tid >> 6, bj = tid & 63;
    const float* Bw = Wu + (size_t)e * H_DIM * I_DIM;
    float acc[4][4] = {};
    for (int k0 = 0; k0 < H_DIM; k0 += 16) {
#pragma unroll
        for (int q = 0; q < 4; ++q) {
            int i = ar + q * 16;
            int p = plist[i];
            As[ak][i] = (p >= 0) ? x[(size_t)(p >> 2) * H_DIM + k0 + ak] : 0.f;
        }
#pragma unroll
        for (int q = 0; q < 4; ++q) {
            int kk = bk + q * 4;
            Bs[kk][bj] = Bw[(size_t)(k0 + kk) * I_DIM + n0 + bj];
        }
        __syncthreads();
#pragma unroll
        for (int kk = 0; kk < 16; ++kk) {
            const float4 a4 = *(const float4*)&As[kk][ty * 4];
            const float4 b4 = *(const float4*)&Bs[kk][tx * 4];
            const float av[4] = {a4.x, a4.y, a4.z, a4.w};
            const float bv[4] = {b4.x, b4.y, b4.z, b4.w};
#pragma unroll
            for (int ii = 0; ii < 4; ++ii)
#pragma unroll
                for (int jj = 0; jj < 4; ++jj)
                    acc[ii][jj] = fmaf(av[ii], bv[jj], acc[ii][jj]);
        }
        __syncthreads();
    }
#pragma unroll
    for (int ii = 0; ii < 4; ++ii) {
        int p = plist[ty * 4 + ii];
        if (p < 0) continue;
        size_t base = (size_t)(p - 4 * t0) * I_DIM + n0 + tx * 4;
#pragma unroll
        for (int jj = 0; jj < 4; ++jj) {
            float r = acc[ii][jj];
            act[base + jj] = r > 0.f ? r * r : 0.f;
        }
    }
}

// routed down: out[t(p), :] += w(p) * (act[p - 4*t0, :] @ Wd[e])
__global__ __launch_bounds__(256) void routed_down_kernel(
    const float* __restrict__ act, const float* __restrict__ Wd,
    const int* __restrict__ counts, const int* __restrict__ list,
    const float* __restrict__ topkw, float* __restrict__ out, int t0, int t1)
{
    const int e = blockIdx.z;
    const int cnt = counts[e];
    const int m0 = blockIdx.x * 64;
    if (m0 >= cnt) return;

    __shared__ int plist[64];
    __shared__ float As[16][68];
    __shared__ float Bs[16][64];
    const int tid = threadIdx.x;
    if (tid < 64) {
        int p = -1;
        if (m0 + tid < cnt) {
            p = list[e * T_TOT + m0 + tid];
            int t = p >> 2;
            if (t < t0 || t >= t1) p = -1;
        }
        plist[tid] = p;
    }
    __syncthreads();

    const int n0 = blockIdx.y * 64;
    const int tx = tid & 15, ty = tid >> 4;
    const int ar = tid >> 4, ak = tid & 15;
    const int bk = tid >> 6, bj = tid & 63;
    const float* Bw = Wd + (size_t)e * I_DIM * H_DIM;
    float acc[4][4] = {};
    for (int k0 = 0; k0 < I_DIM; k0 += 16) {
#pragma unroll
        for (int q = 0; q < 4; ++q) {
            int i = ar + q * 16;
            int p = plist[i];
            As[ak][i] = (p >= 0) ? act[(size_t)(p - 4 * t0) * I_DIM + k0 + ak] : 0.f;
        }
#pragma unroll
        for (int q = 0; q < 4; ++q) {
            int kk = bk + q * 4;
            Bs[kk][bj] = Bw[(size_t)(k0 + kk) * H_DIM + n0 + bj];
        }
        __syncthreads();
#pragma unroll
        for (int kk = 0; kk < 16; ++kk) {
            const float4 a4 = *(const float4*)&As[kk][ty * 4];
            const float4 b4 = *(const float4*)&Bs[kk][tx * 4];
            const float av[4] = {a4.x, a4.y, a4.z, a4.w};
            const float bv[4] = {b4.x, b4.y, b4.z, b4.w};
#pragma unroll
            for (int ii = 0; ii < 4; ++ii)
#pragma unroll
                for (int jj = 0; jj < 4; ++jj)
                    acc[ii][jj] = fmaf(av[ii], bv[jj], acc[ii][jj]);
        }
        __syncthreads();
    }
#pragma unroll
    for (int ii = 0; ii < 4; ++ii) {
        int p = plist[ty * 4 + ii];
        if (p < 0) continue;
        float w = topkw[p];
        size_t base = (size_t)(p >> 2) * H_DIM + n0 + tx * 4;
#pragma unroll
        for (int jj = 0; jj < 4; ++jj)
            atomicAdd(&out[base + jj], w * acc[ii][jj]);
    }
}

// ---------------- launch ----------------
extern "C" void kernel_launch(void* const* d_in, const int* in_sizes, int n_in,
                              void* d_out, int out_size, void* d_ws, size_t ws_size,
                              hipStream_t stream) {
    const float* x    = (const float*)d_in[0];
    const float* gw   = (const float*)d_in[1];
    const float* eb   = (const float*)d_in[2];
    const float* Wu   = (const float*)d_in[3];
    const float* Wd   = (const float*)d_in[4];
    const float* Wsu  = (const float*)d_in[5];
    const float* Wsd  = (const float*)d_in[6];
    float* out = (float*)d_out;
    char* ws = (char*)d_ws;

    // workspace layout: counts(256B) | list(512KB) | topkw(64KB) | big buffer (hs, then act)
    int*   counts = (int*)ws;
    int*   list   = (int*)(ws + 256);
    float* topkw  = (float*)(ws + 256 + (size_t)E_NUM * T_TOT * 4);
    const size_t o_big = 256 + (size_t)E_NUM * T_TOT * 4 + (size_t)T_TOT * K_SEL * 4;
    float* big = (float*)(ws + o_big);
    size_t big_bytes = (ws_size > o_big) ? ws_size - o_big : 0;

    // both hs and act need 16 KB per token; chunk tokens if workspace is small
    long tc = (long)(big_bytes / ((size_t)SI_DIM * 4));
    tc &= ~63L;
    if (tc < 64) tc = 64;
    if (tc > T_TOT) tc = T_TOT;
    const int Tc = (int)tc;
    const int nch = (T_TOT + Tc - 1) / Tc;

    hipMemsetAsync(counts, 0, 256, stream);
    router_kernel<<<T_TOT, 64, 0, stream>>>(x, gw, eb, counts, list, topkw);

    // shared expert first: it initializes out (plain store)
    for (int c = 0; c < nch; ++c) {
        int t0 = c * Tc;
        int t1 = (t0 + Tc < T_TOT) ? t0 + Tc : T_TOT;
        int mt = (t1 - t0 + 63) / 64;
        shared_up_kernel<<<dim3(mt, SI_DIM / 64), 256, 0, stream>>>(x, Wsu, big, t0, t1);
        shared_down_kernel<<<dim3(mt, H_DIM / 64), 256, 0, stream>>>(big, Wsd, out, t0, t1);
    }
    // routed experts accumulate on top via atomics
    for (int c = 0; c < nch; ++c) {
        int t0 = c * Tc;
        int t1 = (t0 + Tc < T_TOT) ? t0 + Tc : T_TOT;
        routed_up_kernel<<<dim3(T_TOT / 64, I_DIM / 64, E_NUM), 256, 0, stream>>>(
            x, Wu, counts, list, big, t0, t1);
        routed_down_kernel<<<dim3(T_TOT / 64, H_DIM / 64, E_NUM), 256, 0, stream>>>(
            big, Wd, counts, list, topkw, out, t0, t1);
    }
}